// Round 8
// baseline (31.295 us; speedup 1.0000x reference)
//
#include <hip/hip_runtime.h>
#include <utility>

// G=14, B=64, T=2048, H=6
#define Gc 14
#define Hc 6
#define NPc (64*2048)          // B*T points
#define LOG_2PI 1.8378770664093453f

typedef float v2f __attribute__((ext_vector_type(2)));

__device__ __forceinline__ float frsq(float x){ return __builtin_amdgcn_rsqf(x); }

// DPP quad_perm broadcast within lane pairs (1-cycle VALU, no LDS):
//   0xA0 = [0,0,2,2] -> pair gets EVEN lane's value; 0xF5 = [1,1,3,3] -> ODD lane's.
template<int CTRL>
__device__ __forceinline__ float dppf(float x){
    union { float f; int i; } u; u.f = x;
    u.i = __builtin_amdgcn_update_dpp(0, u.i, CTRL, 0xF, 0xF, true);
    return u.f;
}
template<int OQ>
__device__ __forceinline__ float bcast(float x){
    return (OQ == 0) ? dppf<0xA0>(x) : dppf<0xF5>(x);
}

// One gprod on slot pair (I, I+1); head = comp C of v2f J on owner lane OQ.
// Identities (|r*C|==1): x3 = a1*x1 - a2*x2 ; x4 = s2*x1 + s1*x2, with
//   S = rsqrt(C1^2+C2^2), s1=C2*S, s2=C1*S, a1=copysign(s1,C1), a2=copysign(s2,C2).
// logC == 0 exactly -> dropped. Lane0 st = cur, lane1 st = nxt (uniform stream);
// bb duplicated & bit-identical on both lanes.
template<int J, int C, int OQ, int I>
__device__ __forceinline__ void gstep(v2f (&st)[Gc][3], float (&bb)[Gc]){
    const float C1 = bcast<OQ>(st[I][J][C]);
    const float C2 = bcast<OQ>(st[I+1][J][C]);
    const float S  = frsq(fmaf(C1, C1, C2 * C2));   // 1 transcendental per gprod
    const float s1 = C2 * S, s2 = C1 * S;
    const float a1 = copysignf(s1, C1), a2 = copysignf(s2, C2);
    const v2f A1 = {a1, a1}, A2 = {a2, a2}, S1 = {s1, s1}, S2 = {s2, s2};
#pragma unroll
    for (int j = 0; j < 3; ++j){
        const v2f x = st[I][j], y = st[I+1][j];
        st[I][j]     = __builtin_elementwise_fma(x, A1, -(y * A2));
        st[I + 1][j] = __builtin_elementwise_fma(x, S2, y * S1);
    }
    const float x = bb[I], y = bb[I + 1];
    bb[I]     = fmaf(x, a1, -(y * a2));
    bb[I + 1] = fmaf(x, s2, y * s1);
}

// ---- software-pipelined schedule ----
// Phase-1 sweep K (K=0..5, n=14-K slots): gprod i at t = i + 2K; pop/log at t = 13+K.
//   Dep check: p1(K,i) needs p1(K-1,i) [t-1] and p1(K-1,i+1) [t-1]... strictly earlier. OK
// Phase-2 sweep K (n=8-K): gprod i at t = i + 12 + 2K; store at t = 19+K.
//   p2(K,i) needs p1(5,i+1) at t=i+11 < i+12. OK. At any t, active gprods touch
//   DISJOINT slot pairs (stride-2 tiling), so same-tick order is irrelevant.
template<int T, int K>
__device__ __forceinline__ void p1_at(v2f (&st)[Gc][3], float (&bb)[Gc], float &LC){
    constexpr int i = T - 2 * K;
    constexpr int n = Gc - K;
    if constexpr (i >= 0 && i <= n - 2)
        gstep<(K >> 1), (K & 1), 0, (i & 31)>(st, bb);
    if constexpr (i == n - 1)   // one tick after the sweep's last gprod
        LC -= __logf(fabsf(st[n - 1][K >> 1][K & 1]));   // valid on lane0; lane1 discarded
}

template<int T, int K>
__device__ __forceinline__ void p2_at(v2f (&st)[Gc][3], float (&bb)[Gc],
                                      float* __restrict__ outN, float* __restrict__ outB,
                                      int p, int q){
    constexpr int i = T - 12 - 2 * K;
    constexpr int n = (Gc - Hc) - K;   // 8-K
    if constexpr (i >= 0 && i <= n - 2)
        gstep<(K >> 1), (K & 1), 1, (i & 31)>(st, bb);
    if constexpr (i == n - 1){
        constexpr int m = n - 1;       // popped slot -> kept_n[K], kept_b[K]
        if (q){
            v2f* o = (v2f*)(outN + (size_t)K * (NPc * Hc) + (size_t)p * Hc);
            o[0] = st[m][0]; o[1] = st[m][1]; o[2] = st[m][2];
        } else {
            outB[(size_t)K * NPc + p] = bb[m];
        }
    }
}

template<int T>
__device__ __forceinline__ void tick(v2f (&st)[Gc][3], float (&bb)[Gc], float &LC,
                                     float* __restrict__ outN, float* __restrict__ outB,
                                     int p, int q){
    p1_at<T, 0>(st, bb, LC); p1_at<T, 1>(st, bb, LC); p1_at<T, 2>(st, bb, LC);
    p1_at<T, 3>(st, bb, LC); p1_at<T, 4>(st, bb, LC); p1_at<T, 5>(st, bb, LC);
    p2_at<T, 0>(st, bb, outN, outB, p, q); p2_at<T, 1>(st, bb, outN, outB, p, q);
    p2_at<T, 2>(st, bb, outN, outB, p, q); p2_at<T, 3>(st, bb, outN, outB, p, q);
    p2_at<T, 4>(st, bb, outN, outB, p, q); p2_at<T, 5>(st, bb, outN, outB, p, q);
}

template<int... Ts>
__device__ __forceinline__ void run_ticks(std::integer_sequence<int, Ts...>,
                                          v2f (&st)[Gc][3], float (&bb)[Gc], float &LC,
                                          float* __restrict__ outN, float* __restrict__ outB,
                                          int p, int q){
    (tick<Ts>(st, bb, LC, outN, outB, p, q), ...);
}

// NOTE: on this toolchain __launch_bounds__(256, N) caps VGPRs at ~256/N
// (N=4 -> 64 cap -> spill storms in rounds 4 & 6). N=2 -> 128 cap = 4 waves/SIMD
// tier; grid has 4096 waves = 4/SIMD fully resident. State ~98 + pipeline temps.
__global__ void __launch_bounds__(256, 2)
gaussmerge_kernel(const float* __restrict__ cur_in,
                  const float* __restrict__ nxt_in,
                  const float* __restrict__ b_in,
                  float* __restrict__ out)
{
    const int tid = threadIdx.x;
    const int q = tid & 1;                          // 0: cur-owner, 1: nxt-owner
    const int p = blockIdx.x * 128 + (tid >> 1);    // point index

    v2f   st[Gc][3];
    float bb[Gc];

    const float* abase = (q ? nxt_in : cur_in) + (size_t)p * Hc;
    const float* bp    = b_in + p;
#pragma unroll
    for (int g = 0; g < Gc; ++g){
        const v2f* a = (const v2f*)(abase + (size_t)g * (NPc * Hc));
        st[g][0] = a[0]; st[g][1] = a[1]; st[g][2] = a[2];
        bb[g] = bp[(size_t)g * NPc];
    }

    float LC = 0.0f;   // phase-1 log args valid on lane0 only; lane1's LC discarded

    float* outN = out;                               // (6, B, T, H)
    float* outB = out + (size_t)Hc * NPc * Hc;       // (6, B, T)
    float* outL = outB + (size_t)Hc * NPc;           // (B, T)

    // ticks T = 0..24 cover: p1 gprods (t<=17), p1 logs (t<=18),
    // p2 gprods (t<=23), p2 stores (t<=24)
    run_ticks(std::make_integer_sequence<int, 25>{}, st, bb, LC, outN, outB, p, q);

    // ---- epilogue: remaining biases (slots 0,1; identical on both lanes) ----
    LC += -0.5f * (LOG_2PI + bb[0] * bb[0]);
    LC += -0.5f * (LOG_2PI + bb[1] * bb[1]);
    if (q == 0) outL[p] = LC;
}

extern "C" void kernel_launch(void* const* d_in, const int* in_sizes, int n_in,
                              void* d_out, int out_size, void* d_ws, size_t ws_size,
                              hipStream_t stream) {
    const float* cur = (const float*)d_in[0];
    const float* nxt = (const float*)d_in[1];
    const float* bia = (const float*)d_in[2];
    float* out = (float*)d_out;

    // 2 threads per point: 256-thread blocks cover 128 points each.
    dim3 grid((NPc * 2) / 256), block(256);
    gaussmerge_kernel<<<grid, block, 0, stream>>>(cur, nxt, bia, out);
}